// Round 13
// baseline (3653.606 us; speedup 1.0000x reference)
//
#include <hip/hip_runtime.h>
#include <hip/hip_bf16.h>
#include <cmath>

#define HID 512
#define TSTEPS 784
#define BATCH 256
#define NCLS 10
#define NBLK 256
#define NGRP 16     // groups (16 batch rows each) x 16 col-slices (32 cols)

typedef __bf16 bf16x8 __attribute__((ext_vector_type(8)));
typedef float f32x4 __attribute__((ext_vector_type(4)));
typedef float f32x2 __attribute__((ext_vector_type(2)));
typedef int   i32x4 __attribute__((ext_vector_type(4)));

#define SWS(r) (((unsigned)(r) & 7u) << 4)

// LLC-coherent ops (bypass L1+L2; proven cross-XCD-visible rounds 4/5/9/12)
#define LDX4_CC(dst, addr) \
    asm volatile("global_load_dwordx4 %0, %1, off sc0 sc1" : "=v"(dst) : "v"(addr) : "memory")
#define STOREDW_CC(addr, val) \
    asm volatile("global_store_dword %0, %1, off sc0 sc1" :: "v"(addr), "v"(val) : "memory")

__device__ __forceinline__ unsigned lddw_cc_wait(const unsigned* a) {
    unsigned d;
    asm volatile("global_load_dword %0, %1, off sc0 sc1\n\ts_waitcnt vmcnt(0)"
                 : "=v"(d) : "v"(a) : "memory");
    return d;
}

// zero h0+h1 (512KB bf16) + flags, transpose x -> xT[784][256]
__global__ void init_all(const float* __restrict__ x, float* __restrict__ xT,
                         uint4* __restrict__ hz, unsigned* __restrict__ flg) {
    int t = blockIdx.x, tid = threadIdx.x;
    xT[t * BATCH + tid] = x[tid * TSTEPS + t];
    int i = t * 256 + tid;
    if (i < (512 << 10) / 16) hz[i] = make_uint4(0u, 0u, 0u, 0u);
    if (i < NGRP * 64) flg[i] = 0u;
}

__device__ __forceinline__ float sigmoid_f(float v) {
    return __fdividef(1.f, 1.f + __expf(-v));
}
__device__ __forceinline__ float tanh_f(float v) {
    float e = __expf(fminf(fmaxf(2.f * v, -30.f), 30.f));
    return __fdividef(e - 1.f, e + 1.f);
}

// Persistent LSTM: 256 blocks = 16 groups(16 batch rows) x 16 col-slices(32 cols).
// W slice (128 gate-rows x 512) in 128KB LDS; c in registers; h via LLC.
// Readiness: per-(producer,row-quad) sub-flags published by each cell WAVE
// right after its own stores drain (wave-local vmcnt) -- no block-wide drain,
// no end-of-step barrier. Consumer staging threads poll exactly the sub-flag
// covering their rows, so stage loads pipeline behind producer completion.
__global__ __launch_bounds__(512)
void lstm_persist(const float* __restrict__ xT,     // [784][256]
                  const float* __restrict__ W_hh,   // [2048][512] fp32
                  const float* __restrict__ w_in,   // [2048]
                  const float* __restrict__ b_ih,
                  const float* __restrict__ b_hh,
                  __bf16* __restrict__ h0,          // [256][512] bf16
                  __bf16* __restrict__ h1,
                  float* __restrict__ hf,           // [256][512] fp32
                  unsigned* __restrict__ flg)
{
    __shared__ __align__(16) __bf16 wlds[128 * HID];  // 128 KB, XOR-swizzled
    __shared__ __align__(16) __bf16 hlds[16 * HID];   // 16 KB, XOR-swizzled
    __shared__ float gl[4][16][33];                   // gate exchange
    __shared__ float xl[16];

    const int tid  = threadIdx.x;
    const int lane = tid & 63;
    const int w    = tid >> 6;           // wave 0..7
    const int s    = w & 3;              // gate (i,f,g,o)
    const int ch   = w >> 2;             // col half (16 cols each)
    const int bg   = blockIdx.x >> 4;    // group (16)
    const int cs   = blockIdx.x & 15;    // col slice (16)
    const int b0   = bg * 16;
    const int j0   = cs * 32;
    const int rlo  = lane & 15;
    const int khi  = (lane >> 4) * 8;    // elements

    unsigned* flags = flg + bg * 64;     // 64 sub-flags: [cs][quad]

    // ---- stage W slice (128 rows x 512) into LDS once (fp32->bf16, swizzled) ----
    {
        int r = tid >> 2;                // local row 0..127
        int q = tid & 3;
        int gs = r >> 5, jj = r & 31;
        const float* src = W_hh + (size_t)(gs * HID + j0 + jj) * HID + q * 128;
        char* wp = (char*)wlds;
        unsigned rowb = (unsigned)r * (HID * 2);
        unsigned sw   = SWS(r);
        #pragma unroll
        for (int cc = 0; cc < 128; cc += 8) {
            float4 va = *(const float4*)(src + cc);
            float4 vb = *(const float4*)(src + cc + 4);
            bf16x8 pk;
            pk[0]=(__bf16)va.x; pk[1]=(__bf16)va.y; pk[2]=(__bf16)va.z; pk[3]=(__bf16)va.w;
            pk[4]=(__bf16)vb.x; pk[5]=(__bf16)vb.y; pk[6]=(__bf16)vb.z; pk[7]=(__bf16)vb.w;
            *(bf16x8*)(wp + ((rowb + (unsigned)(q * 128 + cc) * 2) ^ sw)) = pk;
        }
    }

    // per-lane acc-init terms: gate s, col j0 + ch*16 + rlo
    float win_l, bias_l;
    {
        int idx = s * HID + j0 + ch * 16 + rlo;
        win_l  = w_in[idx];
        bias_l = b_ih[idx] + b_hh[idx];
    }

    // cell mapping (tid<256): row Rc=tid>>4 (0..15), cols c2,c2+1 (of 32)
    const int Rc = tid >> 4;
    const int c2 = (tid & 15) * 2;
    float creg[2] = {0.f, 0.f};

    // staging mapping: row rS (0..15), segment seg (0..31) of 16 bf16 cols (32B)
    const int rS  = tid & 15;
    const int seg = tid >> 4;
    const unsigned rowbS = (unsigned)rS * (HID * 2);
    const unsigned swS   = SWS(rS);
    const unsigned* myflag = flags + (seg >> 1) * 4 + (rS >> 2);  // producer x quad

    // B-fragment base: local W row rB = s*32 + ch*16 + rlo
    const unsigned rBb = (unsigned)(s * 32 + ch * 16 + rlo) * (HID * 2);
    const unsigned swB = SWS(rlo);
    const char* wbp = (const char*)wlds;
    const char* hbp = (const char*)hlds;
    char* hwp = (char*)hlds;

    __syncthreads();

    for (int t = 0; t < TSTEPS; ++t) {
        const __bf16* hprev = (t & 1) ? h1 : h0;
        __bf16* hnext       = (t & 1) ? h0 : h1;

        // ---- stage: x early; per-thread quad-flag poll; then load ----
        if (tid < 16) xl[tid] = xT[t * BATCH + b0 + tid];
        {
            while (lddw_cc_wait(myflag) < (unsigned)t) {}
            const __bf16* gsrc = hprev + (size_t)(b0 + rS) * HID + seg * 16;
            i32x4 v0, v1;
            LDX4_CC(v0, gsrc);
            LDX4_CC(v1, gsrc + 8);
            asm volatile("s_waitcnt vmcnt(0)" ::: "memory");
            __builtin_amdgcn_sched_barrier(0);
            unsigned base = rowbS + (unsigned)seg * 32u;
            *(i32x4*)(hwp + ((base +  0u) ^ swS)) = v0;
            *(i32x4*)(hwp + ((base + 16u) ^ swS)) = v1;
        }
        __syncthreads();   // A: hlds + xl ready

        // ---- gates tile: 16 rows x 16 cols for gate s, col-half ch ----
        // acc_e pre-loaded with x*w_in + bias (EE); acc_o zero.
        f32x4 acc_e, acc_o = {0.f,0.f,0.f,0.f};
        #pragma unroll
        for (int rr = 0; rr < 4; ++rr)
            acc_e[rr] = xl[(lane >> 4) * 4 + rr] * win_l + bias_l;
        #pragma unroll
        for (int ks = 0; ks < 16; ks += 2) {
            unsigned colb0 = (unsigned)(khi * 2 + ks * 64);
            unsigned colb1 = colb0 + 64u;
            bf16x8 a0 = *(const bf16x8*)(hbp + (((unsigned)rlo * 1024u + colb0) ^ SWS(rlo)));
            bf16x8 b0f = *(const bf16x8*)(wbp + ((rBb + colb0) ^ swB));
            bf16x8 a1 = *(const bf16x8*)(hbp + (((unsigned)rlo * 1024u + colb1) ^ SWS(rlo)));
            bf16x8 b1f = *(const bf16x8*)(wbp + ((rBb + colb1) ^ swB));
            acc_e = __builtin_amdgcn_mfma_f32_16x16x32_bf16(a0, b0f, acc_e, 0, 0, 0);
            acc_o = __builtin_amdgcn_mfma_f32_16x16x32_bf16(a1, b1f, acc_o, 0, 0, 0);
        }
        f32x4 acc0 = acc_e + acc_o;
        #pragma unroll
        for (int rr = 0; rr < 4; ++rr) {
            int rowl = (lane >> 4) * 4 + rr;   // D: col=lane&15, row=(lane>>4)*4+reg
            gl[s][rowl][ch * 16 + rlo] = acc0[rr];
        }
        __syncthreads();   // A2: gl ready (gates already include x*w_in + bias)

        // ---- cell update (tid<256: 2 cols), h store, per-wave drain+publish ----
        if (tid < 256) {
            float hn2[2];
            #pragma unroll
            for (int ii = 0; ii < 2; ++ii) {
                int ccx = c2 + ii;
                float gi = gl[0][Rc][ccx];
                float gf = gl[1][Rc][ccx];
                float gg = gl[2][Rc][ccx];
                float go = gl[3][Rc][ccx];
                float cn = sigmoid_f(gf) * creg[ii] + sigmoid_f(gi) * tanh_f(gg);
                creg[ii] = cn;
                hn2[ii]  = sigmoid_f(go) * tanh_f(cn);
            }
            if (t == TSTEPS - 1) {
                *(f32x2*)(hf + (size_t)(b0 + Rc) * HID + j0 + c2) = (f32x2){hn2[0], hn2[1]};
            } else {
                union { __bf16 b[2]; int i; } u;
                u.b[0] = (__bf16)hn2[0]; u.b[1] = (__bf16)hn2[1];
                __bf16* dst = hnext + (size_t)(b0 + Rc) * HID + j0 + c2;
                STOREDW_CC(dst, u.i);
                // wave-local drain: this wave's quad (rows w*4..w*4+3) is at LLC
                asm volatile("s_waitcnt vmcnt(0)" ::: "memory");
                if ((tid & 63) == 0)
                    STOREDW_CC(flags + cs * 4 + w, (int)(t + 1));
            }
        }
        // no end-of-step barrier: hlds rewrite is after A2 (all MFMA reads done);
        // gl rewrite is after next A (requires cell waves to have arrived).
    }
}

// out[b][j] = h_T[b] . W_lin[j] + b_lin[j]
__global__ void head(const float* __restrict__ hfp, const float* __restrict__ Wl,
                     const float* __restrict__ bl_, float* __restrict__ out)
{
    __shared__ float hr[HID];
    int b = blockIdx.x;
    for (int k = threadIdx.x; k < HID; k += blockDim.x) hr[k] = hfp[b * HID + k];
    __syncthreads();
    int j = threadIdx.x;
    if (j < NCLS) {
        float acc = bl_[j];
        for (int k = 0; k < HID; ++k) acc += hr[k] * Wl[j * HID + k];
        out[b * NCLS + j] = acc;
    }
}

extern "C" void kernel_launch(void* const* d_in, const int* in_sizes, int n_in,
                              void* d_out, int out_size, void* d_ws, size_t ws_size,
                              hipStream_t stream) {
    const float* inputs = (const float*)d_in[0];
    const float* W_ih   = (const float*)d_in[1];
    const float* W_hh   = (const float*)d_in[2];
    const float* b_ih   = (const float*)d_in[3];
    const float* b_hh   = (const float*)d_in[4];
    const float* W_lin  = (const float*)d_in[5];
    const float* b_lin  = (const float*)d_in[6];

    // ws: h0 256K | h1 256K | hf 512K | xT 784K | flags 4K
    const size_t OFS_H1  = 256u << 10;
    const size_t OFS_HF  = 512u << 10;
    const size_t OFS_XT  = 1024u << 10;
    const size_t OFS_FLG = OFS_XT + (size_t)TSTEPS * BATCH * 4;   // 128B-aligned
    const size_t NEEDED  = OFS_FLG + NGRP * 64 * 4;
    if (ws_size < NEEDED) return;

    char* ws = (char*)d_ws;
    __bf16* h0 = (__bf16*)ws;
    __bf16* h1 = (__bf16*)(ws + OFS_H1);
    float*  hf = (float*)(ws + OFS_HF);
    float*  xT = (float*)(ws + OFS_XT);
    unsigned* flg = (unsigned*)(ws + OFS_FLG);

    init_all<<<TSTEPS, BATCH, 0, stream>>>(inputs, xT, (uint4*)h0, flg);

    lstm_persist<<<NBLK, 512, 0, stream>>>(xT, W_hh, W_ih, b_ih, b_hh,
                                           h0, h1, hf, flg);

    head<<<BATCH, 64, 0, stream>>>(hf, W_lin, b_lin, (float*)d_out);
}

// Round 14
// 2697.780 us; speedup vs baseline: 1.3543x; 1.3543x over previous
//
#include <hip/hip_runtime.h>
#include <hip/hip_bf16.h>
#include <cmath>

#define HID 512
#define TSTEPS 784
#define BATCH 256
#define NCLS 10
#define NBLK 256
#define NGRP 16     // groups (16 batch rows each) x 16 col-slices (32 cols)

typedef __bf16 bf16x8 __attribute__((ext_vector_type(8)));
typedef float f32x4 __attribute__((ext_vector_type(4)));
typedef float f32x2 __attribute__((ext_vector_type(2)));
typedef int   i32x4 __attribute__((ext_vector_type(4)));

#define SWS(r) (((unsigned)(r) & 7u) << 4)

// LLC-coherent ops (bypass L1+L2; proven cross-XCD-visible rounds 4/5/9/12)
#define LDX4_CC(dst, addr) \
    asm volatile("global_load_dwordx4 %0, %1, off sc0 sc1" : "=v"(dst) : "v"(addr) : "memory")
#define STOREDW_CC(addr, val) \
    asm volatile("global_store_dword %0, %1, off sc0 sc1" :: "v"(addr), "v"(val) : "memory")

__device__ __forceinline__ unsigned lddw_cc_wait(const unsigned* a) {
    unsigned d;
    asm volatile("global_load_dword %0, %1, off sc0 sc1\n\ts_waitcnt vmcnt(0)"
                 : "=v"(d) : "v"(a) : "memory");
    return d;
}

// zero h0+h1 (512KB bf16) + flags, transpose x -> xT[784][256]
__global__ void init_all(const float* __restrict__ x, float* __restrict__ xT,
                         uint4* __restrict__ hz, unsigned* __restrict__ flg) {
    int t = blockIdx.x, tid = threadIdx.x;
    xT[t * BATCH + tid] = x[tid * TSTEPS + t];
    int i = t * 256 + tid;
    if (i < (512 << 10) / 16) hz[i] = make_uint4(0u, 0u, 0u, 0u);
    if (i < NGRP * 64) flg[i] = 0u;
}

__device__ __forceinline__ float sigmoid_f(float v) {
    return __fdividef(1.f, 1.f + __expf(-v));
}
__device__ __forceinline__ float tanh_f(float v) {
    float e = __expf(fminf(fmaxf(2.f * v, -30.f), 30.f));
    return __fdividef(e - 1.f, e + 1.f);
}

// Persistent LSTM: 256 blocks = 16 groups(16 batch rows) x 16 col-slices(32 cols).
// W slice (128 gate-rows x 512) in 128KB LDS; c in registers; h via LLC.
// r12 publish/poll protocol (drain+barrier+single flag; per-thread poll with
// sleep). NEW: coalesced staging (consecutive lanes -> consecutive 32B),
// x*w_in+bias folded into MFMA acc init, cell on all 512 threads.
__global__ __launch_bounds__(512)
void lstm_persist(const float* __restrict__ xT,     // [784][256]
                  const float* __restrict__ W_hh,   // [2048][512] fp32
                  const float* __restrict__ w_in,   // [2048]
                  const float* __restrict__ b_ih,
                  const float* __restrict__ b_hh,
                  __bf16* __restrict__ h0,          // [256][512] bf16
                  __bf16* __restrict__ h1,
                  float* __restrict__ hf,           // [256][512] fp32
                  unsigned* __restrict__ flg)
{
    __shared__ __align__(16) __bf16 wlds[128 * HID];  // 128 KB, XOR-swizzled
    __shared__ __align__(16) __bf16 hlds[16 * HID];   // 16 KB, XOR-swizzled
    __shared__ float gl[4][16][33];                   // gate exchange
    __shared__ float xl[16];

    const int tid  = threadIdx.x;
    const int lane = tid & 63;
    const int w    = tid >> 6;           // wave 0..7
    const int s    = w & 3;              // gate (i,f,g,o)
    const int ch   = w >> 2;             // col half (16 cols each)
    const int bg   = blockIdx.x >> 4;    // group (16)
    const int cs   = blockIdx.x & 15;    // col slice (16)
    const int b0   = bg * 16;
    const int j0   = cs * 32;
    const int rlo  = lane & 15;
    const int khi  = (lane >> 4) * 8;    // elements

    unsigned* flags = flg + bg * 64;     // 256B-separated per-group flag line

    // ---- stage W slice (128 rows x 512) into LDS once (fp32->bf16, swizzled) ----
    {
        int r = tid >> 2;                // local row 0..127
        int q = tid & 3;
        int gs = r >> 5, jj = r & 31;
        const float* src = W_hh + (size_t)(gs * HID + j0 + jj) * HID + q * 128;
        char* wp = (char*)wlds;
        unsigned rowb = (unsigned)r * (HID * 2);
        unsigned sw   = SWS(r);
        #pragma unroll
        for (int cc = 0; cc < 128; cc += 8) {
            float4 va = *(const float4*)(src + cc);
            float4 vb = *(const float4*)(src + cc + 4);
            bf16x8 pk;
            pk[0]=(__bf16)va.x; pk[1]=(__bf16)va.y; pk[2]=(__bf16)va.z; pk[3]=(__bf16)va.w;
            pk[4]=(__bf16)vb.x; pk[5]=(__bf16)vb.y; pk[6]=(__bf16)vb.z; pk[7]=(__bf16)vb.w;
            *(bf16x8*)(wp + ((rowb + (unsigned)(q * 128 + cc) * 2) ^ sw)) = pk;
        }
    }

    // per-lane acc-init terms: gate s, col j0 + ch*16 + rlo
    float win_l, bias_l;
    {
        int idx = s * HID + j0 + ch * 16 + rlo;
        win_l  = w_in[idx];
        bias_l = b_ih[idx] + b_hh[idx];
    }

    // cell mapping (all 512): row Rc = tid>>5 (0..15), col = tid&31 (of 32)
    const int Rc  = tid >> 5;
    const int col = tid & 31;
    float creg = 0.f;

    // staging mapping (COALESCED): row rS = tid>>5, seg = tid&31 (32B each);
    // consecutive lanes -> consecutive 32B of one h row (full line merging)
    const int rS  = tid >> 5;
    const int seg = tid & 31;
    const unsigned rowbS = (unsigned)rS * (HID * 2);
    const unsigned swS   = SWS(rS);
    const unsigned* myflag = flags + (seg >> 1);   // producer of my 16 cols

    // B-fragment base: local W row rB = s*32 + ch*16 + rlo
    const unsigned rBb = (unsigned)(s * 32 + ch * 16 + rlo) * (HID * 2);
    const unsigned swB = SWS(rlo);
    const char* wbp = (const char*)wlds;
    const char* hbp = (const char*)hlds;
    char* hwp = (char*)hlds;

    __syncthreads();

    for (int t = 0; t < TSTEPS; ++t) {
        const __bf16* hprev = (t & 1) ? h1 : h0;
        __bf16* hnext       = (t & 1) ? h0 : h1;

        // ---- stage: x early; per-thread producer-flag poll; coalesced load ----
        if (tid < 16) xl[tid] = xT[t * BATCH + b0 + tid];
        {
            while (lddw_cc_wait(myflag) < (unsigned)t) __builtin_amdgcn_s_sleep(1);
            const __bf16* gsrc = hprev + (size_t)(b0 + rS) * HID + seg * 16;
            i32x4 v0, v1;
            LDX4_CC(v0, gsrc);
            LDX4_CC(v1, gsrc + 8);
            asm volatile("s_waitcnt vmcnt(0)" ::: "memory");
            __builtin_amdgcn_sched_barrier(0);
            unsigned base = rowbS + (unsigned)seg * 32u;
            *(i32x4*)(hwp + ((base +  0u) ^ swS)) = v0;
            *(i32x4*)(hwp + ((base + 16u) ^ swS)) = v1;
        }
        __syncthreads();   // A: hlds + xl ready

        // ---- gates tile: 16 rows x 16 cols for gate s, col-half ch ----
        // acc_e seeded with x*w_in + bias; acc_o zero.
        f32x4 acc_e, acc_o = {0.f,0.f,0.f,0.f};
        #pragma unroll
        for (int rr = 0; rr < 4; ++rr)
            acc_e[rr] = xl[(lane >> 4) * 4 + rr] * win_l + bias_l;
        #pragma unroll
        for (int ks = 0; ks < 16; ks += 2) {
            unsigned colb0 = (unsigned)(khi * 2 + ks * 64);
            unsigned colb1 = colb0 + 64u;
            bf16x8 a0 = *(const bf16x8*)(hbp + (((unsigned)rlo * 1024u + colb0) ^ SWS(rlo)));
            bf16x8 b0f = *(const bf16x8*)(wbp + ((rBb + colb0) ^ swB));
            bf16x8 a1 = *(const bf16x8*)(hbp + (((unsigned)rlo * 1024u + colb1) ^ SWS(rlo)));
            bf16x8 b1f = *(const bf16x8*)(wbp + ((rBb + colb1) ^ swB));
            acc_e = __builtin_amdgcn_mfma_f32_16x16x32_bf16(a0, b0f, acc_e, 0, 0, 0);
            acc_o = __builtin_amdgcn_mfma_f32_16x16x32_bf16(a1, b1f, acc_o, 0, 0, 0);
        }
        f32x4 acc0 = acc_e + acc_o;
        #pragma unroll
        for (int rr = 0; rr < 4; ++rr) {
            int rowl = (lane >> 4) * 4 + rr;   // D: col=lane&15, row=(lane>>4)*4+reg
            gl[s][rowl][ch * 16 + rlo] = acc0[rr];
        }
        __syncthreads();   // A2: gl ready (gates include x*w_in + bias)

        // ---- cell update (all 512, 1 col each), pair-packed h store ----
        {
            float gi = gl[0][Rc][col];
            float gf = gl[1][Rc][col];
            float gg = gl[2][Rc][col];
            float go = gl[3][Rc][col];
            float cn = sigmoid_f(gf) * creg + sigmoid_f(gi) * tanh_f(gg);
            creg = cn;
            float hn = sigmoid_f(go) * tanh_f(cn);
            float hn_o = __shfl_xor(hn, 1);      // partner col's value
            if (t == TSTEPS - 1) {
                if (!(tid & 1))
                    *(f32x2*)(hf + (size_t)(b0 + Rc) * HID + j0 + col) = (f32x2){hn, hn_o};
            } else {
                if (!(tid & 1)) {
                    union { __bf16 b[2]; int i; } u;
                    u.b[0] = (__bf16)hn; u.b[1] = (__bf16)hn_o;
                    __bf16* dst = hnext + (size_t)(b0 + Rc) * HID + j0 + col;
                    STOREDW_CC(dst, u.i);
                }
            }
        }
        if (t == TSTEPS - 1) break;

        // ---- drain + publish (flag = t+1), r12-proven shape ----
        asm volatile("s_waitcnt vmcnt(0)" ::: "memory");   // own h stores at LLC
        __syncthreads();                                   // B: whole block drained
        if (tid == 0) STOREDW_CC(flags + cs, (int)(t + 1));
    }
}

// out[b][j] = h_T[b] . W_lin[j] + b_lin[j]
__global__ void head(const float* __restrict__ hfp, const float* __restrict__ Wl,
                     const float* __restrict__ bl_, float* __restrict__ out)
{
    __shared__ float hr[HID];
    int b = blockIdx.x;
    for (int k = threadIdx.x; k < HID; k += blockDim.x) hr[k] = hfp[b * HID + k];
    __syncthreads();
    int j = threadIdx.x;
    if (j < NCLS) {
        float acc = bl_[j];
        for (int k = 0; k < HID; ++k) acc += hr[k] * Wl[j * HID + k];
        out[b * NCLS + j] = acc;
    }
}

extern "C" void kernel_launch(void* const* d_in, const int* in_sizes, int n_in,
                              void* d_out, int out_size, void* d_ws, size_t ws_size,
                              hipStream_t stream) {
    const float* inputs = (const float*)d_in[0];
    const float* W_ih   = (const float*)d_in[1];
    const float* W_hh   = (const float*)d_in[2];
    const float* b_ih   = (const float*)d_in[3];
    const float* b_hh   = (const float*)d_in[4];
    const float* W_lin  = (const float*)d_in[5];
    const float* b_lin  = (const float*)d_in[6];

    // ws: h0 256K | h1 256K | hf 512K | xT 784K | flags 4K
    const size_t OFS_H1  = 256u << 10;
    const size_t OFS_HF  = 512u << 10;
    const size_t OFS_XT  = 1024u << 10;
    const size_t OFS_FLG = OFS_XT + (size_t)TSTEPS * BATCH * 4;   // 128B-aligned
    const size_t NEEDED  = OFS_FLG + NGRP * 64 * 4;
    if (ws_size < NEEDED) return;

    char* ws = (char*)d_ws;
    __bf16* h0 = (__bf16*)ws;
    __bf16* h1 = (__bf16*)(ws + OFS_H1);
    float*  hf = (float*)(ws + OFS_HF);
    float*  xT = (float*)(ws + OFS_XT);
    unsigned* flg = (unsigned*)(ws + OFS_FLG);

    init_all<<<TSTEPS, BATCH, 0, stream>>>(inputs, xT, (uint4*)h0, flg);

    lstm_persist<<<NBLK, 512, 0, stream>>>(xT, W_hh, W_ih, b_ih, b_hh,
                                           h0, h1, hf, flg);

    head<<<BATCH, 64, 0, stream>>>(hf, W_lin, b_lin, (float*)d_out);
}